// Round 5
// baseline (197.435 us; speedup 1.0000x reference)
//
#include <hip/hip_runtime.h>
#include <stdint.h>

#define B_ 128
#define N_ 512
#define I_ 256
#define M_ 32
#define D_ 16

typedef __attribute__((ext_vector_type(4))) float f32x4;
typedef __attribute__((ext_vector_type(4))) float float4v;
typedef __attribute__((ext_vector_type(8))) short short8;     // 8 bf16 MFMA frag
typedef __attribute__((ext_vector_type(4))) unsigned int u32x4;
typedef __attribute__((ext_vector_type(4))) unsigned short ushort4v;

__device__ __forceinline__ float bf2f(unsigned short u) {
    union { unsigned int i; float f; } v; v.i = ((unsigned int)u) << 16; return v.f;
}
__device__ __forceinline__ unsigned short f2bf(float f) {
    union { float f; unsigned int i; } v; v.f = f;
    unsigned int r = v.i + 0x7FFFu + ((v.i >> 16) & 1u);   // RNE
    return (unsigned short)(r >> 16);
}

__device__ __forceinline__ void gload16(const void* g, void* l) {
    __builtin_amdgcn_global_load_lds(
        (const __attribute__((address_space(1))) void*)g,
        (__attribute__((address_space(3))) void*)l, 16, 0, 0);
}

// -----------------------------------------------------------------------------
// Kernel 0: x[b][n][i] fp32 -> xT[n][b][i] bf16.  Pure streaming (calibration).
// -----------------------------------------------------------------------------
__global__ __launch_bounds__(256) void conv_x(const float* __restrict__ x,
                                              unsigned short* __restrict__ xT) {
    const int rid = blockIdx.x * 4 + (threadIdx.x >> 6);   // rid = b*512 + n
    const int i0  = (threadIdx.x & 63) * 4;
    const int b   = rid >> 9;
    const int n   = rid & 511;
    float4v v = *(const float4v*)(x + (size_t)rid * I_ + i0);
    ushort4v h;
    h[0] = f2bf(v[0]); h[1] = f2bf(v[1]); h[2] = f2bf(v[2]); h[3] = f2bf(v[3]);
    *(ushort4v*)(xT + ((size_t)(n * B_ + b)) * I_ + i0) = h;
}

// Read one bf16 B-fragment (8 consecutive k) from XOR-swizzled fp32 LDS row.
// Granule (16B) g of row r lives at LDS granule g ^ (r&15).
__device__ __forceinline__ short8 ldfragB(const float* rowp, int r15, int g0) {
    const f32x4* rp = (const f32x4*)rowp;
    f32x4 lo = rp[g0 ^ r15];
    f32x4 hi = rp[(g0 + 1) ^ r15];
    unsigned int u0, u1, u2, u3;
    asm("v_cvt_pk_bf16_f32 %0, %1, %2" : "=v"(u0) : "v"(lo[0]), "v"(lo[1]));
    asm("v_cvt_pk_bf16_f32 %0, %1, %2" : "=v"(u1) : "v"(lo[2]), "v"(lo[3]));
    asm("v_cvt_pk_bf16_f32 %0, %1, %2" : "=v"(u2) : "v"(hi[0]), "v"(hi[1]));
    asm("v_cvt_pk_bf16_f32 %0, %1, %2" : "=v"(u3) : "v"(hi[2]), "v"(hi[3]));
    u32x4 uv = {u0, u1, u2, u3};
    return __builtin_bit_cast(short8, uv);
}

// -----------------------------------------------------------------------------
// Kernel 1: inputs_hat[b,m,n,d] = sum_i x[b,n,i] * W[m,n,d,i]
// Block (mc in 0..7, n): 128 b-rows x 64 cols (m = mc*4..+4, all d), FULL K.
// W staged full-K fp32 into 64KB LDS: one gload_lds instr = one contiguous
// 1KB W row (lane-granule XOR-permuted within the row; involution on read).
// A read directly from L2-resident xT (bf16) into regs, rolling 4 K-steps.
// One barrier per block; overlap comes from 2 blocks/CU.
// -----------------------------------------------------------------------------
__global__ __launch_bounds__(256) void hat_gemm(const float* __restrict__ W,
                                                const unsigned short* __restrict__ xT,
                                                unsigned short* __restrict__ hat) {
    __shared__ float Bs[64][256];       // 64 KB: [col = m_local*16+d][k], swizzled

    const int n    = blockIdx.y;
    const int mc   = blockIdx.x;        // m in [mc*4, mc*4+4)
    const int tid  = threadIdx.x;
    const int lane = tid & 63;
    const int w    = tid >> 6;          // wave 0..3 -> b-rows [w*32, w*32+32)
    const int l15  = lane & 15;

    // ---- stage: wave w stages cols [w*16, w*16+16) = m_local w, d = 0..15 ----
    // One instr per row: 64 lanes x 16B = the full 1KB W row (granule-permuted).
    {
        const size_t mbase = (((size_t)(mc * 4 + w) * N_ + n) * D_) * I_;
        #pragma unroll
        for (int j = 0; j < 16; ++j) {
            const float* src = W + mbase + (size_t)j * I_ + ((lane ^ j) << 2);
            gload16(src, &Bs[w * 16 + j][0]);
        }
    }

    // ---- A preload: rolling 4 K-steps, 2 row-tiles (w*32+0/16) ----
    const unsigned short* xrow0 = xT + ((size_t)(n * B_) + w * 32 + l15) * I_;
    auto loadA = [&](int a, int ks) -> short8 {
        return *(const short8*)(xrow0 + (size_t)a * 16 * I_ + ks * 32 + (lane >> 4) * 8);
    };

    short8 pa0[4], pa1[4];
    #pragma unroll
    for (int j = 0; j < 4; ++j) { pa0[j] = loadA(0, j); pa1[j] = loadA(1, j); }

    f32x4 acc[2][4];
    #pragma unroll
    for (int a = 0; a < 2; ++a)
        #pragma unroll
        for (int c = 0; c < 4; ++c) { f32x4 z = {0.f, 0.f, 0.f, 0.f}; acc[a][c] = z; }

    __syncthreads();   // drains gload_lds + preloads; Bs visible to all waves

    // ---- compute: 8 K-steps of 32 ----
    #pragma unroll
    for (int ks = 0; ks < 8; ++ks) {
        short8 a0 = pa0[ks & 3];
        short8 a1 = pa1[ks & 3];
        if (ks < 4) { pa0[ks & 3] = loadA(0, ks + 4); pa1[ks & 3] = loadA(1, ks + 4); }
        const int g0 = ks * 8 + (lane >> 4) * 2;
        #pragma unroll
        for (int ct = 0; ct < 4; ++ct) {
            short8 bb = ldfragB(&Bs[ct * 16 + l15][0], l15, g0);
            acc[0][ct] = __builtin_amdgcn_mfma_f32_16x16x32_bf16(a0, bb, acc[0][ct], 0, 0, 0);
            acc[1][ct] = __builtin_amdgcn_mfma_f32_16x16x32_bf16(a1, bb, acc[1][ct], 0, 0, 0);
        }
    }

    // ---- epilogue: D lane map: col = lane&15, row = (lane>>4)*4 + r ----
    const int d  = l15;
    const int rq = lane >> 4;
    #pragma unroll
    for (int rt = 0; rt < 2; ++rt) {
        #pragma unroll
        for (int ct = 0; ct < 4; ++ct) {
            const int m = mc * 4 + ct;
            #pragma unroll
            for (int r = 0; r < 4; ++r) {
                const int brow = w * 32 + rt * 16 + rq * 4 + r;
                const size_t idx = (((size_t)brow * M_ + m) * N_ + n) * D_ + d;
                hat[idx] = f2bf(acc[rt][ct][r]);
            }
        }
    }
}

// -----------------------------------------------------------------------------
// Kernel 2: dynamic routing (3 iterations), one block per batch element b.
// (unchanged — known-correct)
// -----------------------------------------------------------------------------
__global__ __launch_bounds__(512) void routing(const unsigned short* __restrict__ hat,
                                               float* __restrict__ out) {
    __shared__ float blog[M_][N_];
    __shared__ float cmax[N_];
    __shared__ float rcsum[N_];

    const int b    = blockIdx.x;
    const int tid  = threadIdx.x;
    const int lane = tid & 63;
    const int w    = tid >> 6;

    #pragma unroll
    for (int m = 0; m < M_; ++m) blog[m][tid] = 0.f;
    __syncthreads();

    float ov[4][16];

    for (int it = 0; it < 3; ++it) {
        {
            float mx = -3.4e38f;
            #pragma unroll
            for (int m = 0; m < M_; ++m) mx = fmaxf(mx, blog[m][tid]);
            float s = 0.f;
            #pragma unroll
            for (int m = 0; m < M_; ++m) s += __expf(blog[m][tid] - mx);
            cmax[tid]  = mx;
            rcsum[tid] = 1.f / s;
        }
        __syncthreads();

        float sacc[4][16];
        #pragma unroll
        for (int q = 0; q < 4; ++q)
            #pragma unroll
            for (int dd = 0; dd < 16; ++dd) sacc[q][dd] = 0.f;

        for (int r = 0; r < 8; ++r) {
            const int nn = r * 64 + lane;
            #pragma unroll
            for (int q = 0; q < 4; ++q) {
                const int m = w * 4 + q;
                const float cm = __expf(blog[m][nn] - cmax[nn]) * rcsum[nn];
                const size_t base = (((size_t)b * M_ + m) * N_ + nn) * D_;
                short8 h0 = *(const short8*)(hat + base);
                short8 h1 = *(const short8*)(hat + base + 8);
                #pragma unroll
                for (int dd = 0; dd < 8; ++dd) {
                    sacc[q][dd]     += cm * bf2f((unsigned short)h0[dd]);
                    sacc[q][8 + dd] += cm * bf2f((unsigned short)h1[dd]);
                }
            }
        }
        #pragma unroll
        for (int off = 32; off >= 1; off >>= 1) {
            #pragma unroll
            for (int q = 0; q < 4; ++q)
                #pragma unroll
                for (int dd = 0; dd < 16; ++dd)
                    sacc[q][dd] += __shfl_xor(sacc[q][dd], off, 64);
        }
        #pragma unroll
        for (int q = 0; q < 4; ++q) {
            float s2 = 0.f;
            #pragma unroll
            for (int dd = 0; dd < 16; ++dd) s2 += sacc[q][dd] * sacc[q][dd];
            const float scale = s2 / (1.f + s2) / sqrtf(s2 + 1e-7f);
            #pragma unroll
            for (int dd = 0; dd < 16; ++dd) ov[q][dd] = scale * sacc[q][dd];
        }

        if (it < 2) {
            for (int r = 0; r < 8; ++r) {
                const int nn = r * 64 + lane;
                #pragma unroll
                for (int q = 0; q < 4; ++q) {
                    const int m = w * 4 + q;
                    const size_t base = (((size_t)b * M_ + m) * N_ + nn) * D_;
                    short8 h0 = *(const short8*)(hat + base);
                    short8 h1 = *(const short8*)(hat + base + 8);
                    float dot = 0.f;
                    #pragma unroll
                    for (int dd = 0; dd < 8; ++dd) {
                        dot += ov[q][dd]     * bf2f((unsigned short)h0[dd]);
                        dot += ov[q][8 + dd] * bf2f((unsigned short)h1[dd]);
                    }
                    blog[m][nn] += dot;
                }
            }
        }
        __syncthreads();
    }

    if (lane == 0) {
        #pragma unroll
        for (int q = 0; q < 4; ++q) {
            const int m = w * 4 + q;
            #pragma unroll
            for (int c4 = 0; c4 < 4; ++c4) {
                float4v v;
                v[0] = ov[q][c4 * 4 + 0];
                v[1] = ov[q][c4 * 4 + 1];
                v[2] = ov[q][c4 * 4 + 2];
                v[3] = ov[q][c4 * 4 + 3];
                *(float4v*)&out[((size_t)b * M_ + m) * D_ + c4 * 4] = v;
            }
        }
    }
}

extern "C" void kernel_launch(void* const* d_in, const int* in_sizes, int n_in,
                              void* d_out, int out_size, void* d_ws, size_t ws_size,
                              hipStream_t stream) {
    const float* x = (const float*)d_in[0];        // [128, 512, 256] fp32
    const float* W = (const float*)d_in[1];        // [32, 512, 16, 256] fp32
    unsigned short* hat = (unsigned short*)d_ws;   // bf16 [128,32,512,16] = 64 MB
    unsigned short* xT  = (unsigned short*)((char*)d_ws + (size_t)64 * 1024 * 1024); // bf16 [512,128,256] = 32 MB
    float* out = (float*)d_out;                    // fp32 [128,32,16]

    conv_x<<<dim3((B_ * N_) / 4), dim3(256), 0, stream>>>(x, xT);
    hat_gemm<<<dim3(8, N_), dim3(256), 0, stream>>>(W, xT, hat);
    routing<<<dim3(B_), dim3(512), 0, stream>>>(hat, out);
}